// Round 1
// baseline (308.247 us; speedup 1.0000x reference)
//
#include <hip/hip_runtime.h>

#define B_ 8
#define H_ 64
#define W_ 64
#define DIM_ 768
#define MID_ 96
#define NPIX_ 32768

typedef float f32x4 __attribute__((ext_vector_type(4)));
typedef __bf16 bf16x8 __attribute__((ext_vector_type(8)));

// ---------------------------------------------------------------------------
// K0: per-row LayerNorm stats (mean, rstd) for a [32768, 768] fp32 tensor.
// One wave per row; 4 rows per 256-thread block.
// ---------------------------------------------------------------------------
__global__ __launch_bounds__(256) void k_stats(const float* __restrict__ src,
                                               float* __restrict__ stats) {
    const int row = blockIdx.x * 4 + (threadIdx.x >> 6);
    const int lane = threadIdx.x & 63;
    const float* p = src + (size_t)row * DIM_;
    float s = 0.f, sq = 0.f;
#pragma unroll
    for (int i = 0; i < 3; ++i) {
        float4 v = *reinterpret_cast<const float4*>(p + i * 256 + lane * 4);
        s += v.x + v.y + v.z + v.w;
        sq += v.x * v.x + v.y * v.y + v.z * v.z + v.w * v.w;
    }
#pragma unroll
    for (int m = 1; m < 64; m <<= 1) {
        s += __shfl_xor(s, m, 64);
        sq += __shfl_xor(sq, m, 64);
    }
    if (lane == 0) {
        float mean = s * (1.f / 768.f);
        float var = sq * (1.f / 768.f) - mean * mean;
        stats[row * 2 + 0] = mean;
        stats[row * 2 + 1] = rsqrtf(var + 1e-6f);
    }
}

// ---------------------------------------------------------------------------
// K1: fused LN-normalize + GEMM  out[m,n] = LN(src)[m,:] . Wt[n,:] + bias[n]
// src [32768,768] fp32, Wt [96,768] fp32, out [32768,96] fp32.
// Block: 256 thr = 4 waves, M-tile 64 (wave per 16 rows), full N=96 (6 frags).
// bf16 MFMA 16x16x32; LDS 16B-slot XOR swizzle (slot ^ (row&3)).
// ---------------------------------------------------------------------------
__global__ __launch_bounds__(256) void k_down(const float* __restrict__ src,
        const float* __restrict__ stats, const float* __restrict__ Wt,
        const float* __restrict__ bias, const float* __restrict__ lnw,
        const float* __restrict__ lnb, float* __restrict__ out) {
    __shared__ bf16x8 As[64][4];
    __shared__ bf16x8 Bs[96][4];
    const int t = threadIdx.x;
    const int row0 = blockIdx.x * 64;
    const int arow = t >> 2;   // 0..63
    const int aq = t & 3;      // 8-elem slot
    const float mean = stats[(row0 + arow) * 2 + 0];
    const float rstd = stats[(row0 + arow) * 2 + 1];
    const float* asrc = src + (size_t)(row0 + arow) * DIM_ + aq * 8;

    const int lane = t & 63;
    const int wave = t >> 6;
    const int l15 = lane & 15;
    const int l4 = lane >> 4;

    f32x4 acc[6] = {};

    for (int kt = 0; kt < 24; ++kt) {
        const int k0 = kt * 32;
        if (kt) __syncthreads();
        // stage A (normalize + cast): one 8-float slot per thread
        {
            float4 v0 = *reinterpret_cast<const float4*>(asrc + k0);
            float4 v1 = *reinterpret_cast<const float4*>(asrc + k0 + 4);
            const float* lwp = lnw + k0 + aq * 8;
            const float* lbp = lnb + k0 + aq * 8;
            float4 w0 = *reinterpret_cast<const float4*>(lwp);
            float4 w1 = *reinterpret_cast<const float4*>(lwp + 4);
            float4 b0 = *reinterpret_cast<const float4*>(lbp);
            float4 b1 = *reinterpret_cast<const float4*>(lbp + 4);
            bf16x8 pk;
            pk[0] = (__bf16)((v0.x - mean) * rstd * w0.x + b0.x);
            pk[1] = (__bf16)((v0.y - mean) * rstd * w0.y + b0.y);
            pk[2] = (__bf16)((v0.z - mean) * rstd * w0.z + b0.z);
            pk[3] = (__bf16)((v0.w - mean) * rstd * w0.w + b0.w);
            pk[4] = (__bf16)((v1.x - mean) * rstd * w1.x + b1.x);
            pk[5] = (__bf16)((v1.y - mean) * rstd * w1.y + b1.y);
            pk[6] = (__bf16)((v1.z - mean) * rstd * w1.z + b1.z);
            pk[7] = (__bf16)((v1.w - mean) * rstd * w1.w + b1.w);
            As[arow][aq ^ (arow & 3)] = pk;
        }
        // stage B: 96 rows x 4 slots = 384 items
#pragma unroll
        for (int it = 0; it < 2; ++it) {
            const int idx = t + it * 256;
            if (idx < 384) {
                const int br = idx >> 2, bq = idx & 3;
                const float* wp = Wt + (size_t)br * DIM_ + k0 + bq * 8;
                float4 v0 = *reinterpret_cast<const float4*>(wp);
                float4 v1 = *reinterpret_cast<const float4*>(wp + 4);
                bf16x8 pk;
                pk[0] = (__bf16)v0.x; pk[1] = (__bf16)v0.y;
                pk[2] = (__bf16)v0.z; pk[3] = (__bf16)v0.w;
                pk[4] = (__bf16)v1.x; pk[5] = (__bf16)v1.y;
                pk[6] = (__bf16)v1.z; pk[7] = (__bf16)v1.w;
                Bs[br][bq ^ (br & 3)] = pk;
            }
        }
        __syncthreads();
        const int ar = wave * 16 + l15;
        bf16x8 a = As[ar][l4 ^ (ar & 3)];
#pragma unroll
        for (int f = 0; f < 6; ++f) {
            const int br = f * 16 + l15;
            bf16x8 b = Bs[br][l4 ^ (br & 3)];
            acc[f] = __builtin_amdgcn_mfma_f32_16x16x32_bf16(a, b, acc[f], 0, 0, 0);
        }
    }
    // epilogue: D[row=(l>>4)*4+r][col=l&15]
    const int orow = row0 + wave * 16 + l4 * 4;
#pragma unroll
    for (int f = 0; f < 6; ++f) {
        const int col = f * 16 + l15;
        const float bc = bias[col];
#pragma unroll
        for (int r = 0; r < 4; ++r)
            out[(size_t)(orow + r) * MID_ + col] = acc[f][r] + bc;
    }
}

// ---------------------------------------------------------------------------
// K2: depthwise 3x3 conv (zero pad) + SiLU.  temb [32768,96] fp32 -> y bf16.
// One block per (b,h) row.
// ---------------------------------------------------------------------------
__global__ __launch_bounds__(256) void k_dwconv(const float* __restrict__ temb,
        const float* __restrict__ dww, const float* __restrict__ dwb,
        __bf16* __restrict__ y) {
    __shared__ float wls[96 * 9];
    __shared__ float bls[96];
    const int t = threadIdx.x;
    for (int i = t; i < 96 * 9; i += 256) wls[i] = dww[i];
    if (t < 96) bls[t] = dwb[t];
    __syncthreads();
    const int b = blockIdx.x >> 6, h = blockIdx.x & 63;
    const float* base = temb + (size_t)b * 4096 * MID_;
    for (int o = t; o < 64 * 96; o += 256) {
        const int w = o / 96;
        const int c = o - w * 96;
        float acc = bls[c];
#pragma unroll
        for (int dh = 0; dh < 3; ++dh) {
            const int hh = h + dh - 1;
            if (hh < 0 || hh > 63) continue;
#pragma unroll
            for (int dw = 0; dw < 3; ++dw) {
                const int ww = w + dw - 1;
                if (ww < 0 || ww > 63) continue;
                acc += base[((size_t)hh * 64 + ww) * MID_ + c] * wls[c * 9 + dh * 3 + dw];
            }
        }
        y[((size_t)(b * 64 + h) * 64 + w) * MID_ + c] =
            (__bf16)(acc / (1.f + __expf(-acc)));
    }
}

// ---------------------------------------------------------------------------
// K3: style GEMM (y[32768,96] @ pw_w[192,96]^T + pw_b) fused with modulation:
// common = x_emb * (1 + gamma) + beta  -> bf16 [32768,96].
// Block: M-tile 64, N=192 (12 frags/wave), K=96 fully staged.
// ---------------------------------------------------------------------------
__global__ __launch_bounds__(256) void k_style(const __bf16* __restrict__ y,
        const float* __restrict__ pww, const float* __restrict__ pwb,
        const float* __restrict__ xemb, __bf16* __restrict__ common) {
    __shared__ bf16x8 As[64][12];
    __shared__ bf16x8 Bs[192][12];
    const int t = threadIdx.x;
    const int row0 = blockIdx.x * 64;
    // stage A: 64 x 12 slots
    for (int idx = t; idx < 768; idx += 256) {
        const int r = idx / 12;
        const int s = idx - r * 12;
        As[r][s ^ (r & 3)] =
            *reinterpret_cast<const bf16x8*>(y + (size_t)(row0 + r) * MID_ + s * 8);
    }
    // stage B: 192 x 12
    for (int idx = t; idx < 2304; idx += 256) {
        const int r = idx / 12;
        const int s = idx - r * 12;
        const float* wp = pww + (size_t)r * MID_ + s * 8;
        float4 v0 = *reinterpret_cast<const float4*>(wp);
        float4 v1 = *reinterpret_cast<const float4*>(wp + 4);
        bf16x8 pk;
        pk[0] = (__bf16)v0.x; pk[1] = (__bf16)v0.y;
        pk[2] = (__bf16)v0.z; pk[3] = (__bf16)v0.w;
        pk[4] = (__bf16)v1.x; pk[5] = (__bf16)v1.y;
        pk[6] = (__bf16)v1.z; pk[7] = (__bf16)v1.w;
        Bs[r][s ^ (r & 3)] = pk;
    }
    __syncthreads();
    const int lane = t & 63, wave = t >> 6;
    const int l15 = lane & 15, l4 = lane >> 4;
    f32x4 acc[12] = {};
    const int ar = wave * 16 + l15;
#pragma unroll
    for (int kt = 0; kt < 3; ++kt) {
        bf16x8 a = As[ar][(kt * 4 + l4) ^ (ar & 3)];
#pragma unroll
        for (int f = 0; f < 12; ++f) {
            const int br = f * 16 + l15;
            bf16x8 b = Bs[br][(kt * 4 + l4) ^ (br & 3)];
            acc[f] = __builtin_amdgcn_mfma_f32_16x16x32_bf16(a, b, acc[f], 0, 0, 0);
        }
    }
    const int orow = row0 + wave * 16 + l4 * 4;
#pragma unroll
    for (int f = 0; f < 6; ++f) {
        const int col = f * 16 + l15;
        const float pbg = pwb[col];
        const float pbb = pwb[col + 96];
#pragma unroll
        for (int r = 0; r < 4; ++r) {
            const float g = acc[f][r] + pbg;
            const float bt = acc[f + 6][r] + pbb;
            const float xe = xemb[(size_t)(orow + r) * MID_ + col];
            common[(size_t)(orow + r) * MID_ + col] = (__bf16)(xe * (1.f + g) + bt);
        }
    }
}

// ---------------------------------------------------------------------------
// K4: gvec partial sums: x_emb [8,4096,96] -> part [8,16,96]
// ---------------------------------------------------------------------------
__global__ __launch_bounds__(384) void k_gvec(const float* __restrict__ xemb,
                                              float* __restrict__ part) {
    const int b = blockIdx.x, seg = blockIdx.y;
    const int t = threadIdx.x;
    const int g = t / 96, c = t - g * 96;
    __shared__ float red[4][96];
    const float* p = xemb + ((size_t)b * 4096 + seg * 256) * MID_;
    float s = 0.f;
    for (int i = g; i < 256; i += 4) s += p[(size_t)i * MID_ + c];
    red[g][c] = s;
    __syncthreads();
    if (g == 0)
        part[((size_t)b * 16 + seg) * MID_ + c] =
            red[0][c] + red[1][c] + red[2][c] + red[3][c];
}

// ---------------------------------------------------------------------------
// K5: finish gvec mean, MLP (96->24 relu ->4), softmax -> wts [8,4]
// ---------------------------------------------------------------------------
__global__ __launch_bounds__(128) void k_mlp(const float* __restrict__ part,
        const float* __restrict__ m1w, const float* __restrict__ m1b,
        const float* __restrict__ m2w, const float* __restrict__ m2b,
        float* __restrict__ wts) {
    const int b = blockIdx.x, t = threadIdx.x;
    __shared__ float gv[96];
    __shared__ float hid[24];
    __shared__ float lg[4];
    if (t < 96) {
        float s = 0.f;
        for (int i = 0; i < 16; ++i) s += part[((size_t)b * 16 + i) * MID_ + t];
        gv[t] = s * (1.f / 4096.f);
    }
    __syncthreads();
    if (t < 24) {
        float s = m1b[t];
        for (int c = 0; c < 96; ++c) s += gv[c] * m1w[t * 96 + c];
        hid[t] = fmaxf(s, 0.f);
    }
    __syncthreads();
    if (t < 4) {
        float s = m2b[t];
        for (int j = 0; j < 24; ++j) s += hid[j] * m2w[t * 24 + j];
        lg[t] = s;
    }
    __syncthreads();
    if (t < 4) {
        const float m = fmaxf(fmaxf(lg[0], lg[1]), fmaxf(lg[2], lg[3]));
        const float e = __expf(lg[t] - m);
        const float sum = __expf(lg[0] - m) + __expf(lg[1] - m) +
                          __expf(lg[2] - m) + __expf(lg[3] - m);
        wts[b * 4 + t] = e / sum;
    }
}

// ---------------------------------------------------------------------------
// K6: circular 7x7 conv (== the rfft2/irfft2 product). dyn built in LDS from
// softmax weights * basis. Sliding-window register reuse along w.
// Block: 192 thr = (c 0..95) x (2 w-groups of 16); grid (b, h, half of 32 w).
// ---------------------------------------------------------------------------
__global__ __launch_bounds__(192) void k_circ(const __bf16* __restrict__ common,
        const float* __restrict__ wts, const float* __restrict__ basis,
        __bf16* __restrict__ outc) {
    __shared__ float dyn[49][96];
    const int t = threadIdx.x;
    const int b = blockIdx.x >> 7;
    const int h = (blockIdx.x >> 1) & 63;
    const int wslice = blockIdx.x & 1;
    const float w0 = wts[b * 4 + 0], w1 = wts[b * 4 + 1];
    const float w2 = wts[b * 4 + 2], w3 = wts[b * 4 + 3];
    for (int idx = t; idx < 4704; idx += 192) {
        const int c = idx / 49;
        const int pq = idx - c * 49;
        const size_t off = (size_t)c * 49 + pq;   // basis[k][c][pq], k-stride 4704
        dyn[pq][c] = w0 * basis[off] + w1 * basis[off + 4704] +
                     w2 * basis[off + 9408] + w3 * basis[off + 14112];
    }
    __syncthreads();
    const int c = t % 96;
    const int wg = t / 96;
    const int wbase = wslice * 32 + wg * 16;
    const __bf16* cb = common + (size_t)b * 4096 * MID_ + c;
    float acc[16] = {};
#pragma unroll 1
    for (int p = 0; p < 7; ++p) {
        const int hh = (h + 3 - p) & 63;
        const __bf16* rp = cb + (size_t)hh * 64 * MID_;
        float dynr[7];
#pragma unroll
        for (int q = 0; q < 7; ++q) dynr[q] = dyn[p * 7 + q][c];
#pragma unroll
        for (int i = 0; i < 22; ++i) {
            const int ww = (wbase - 3 + i) & 63;
            const float cm = (float)rp[(size_t)ww * MID_];
#pragma unroll
            for (int q = 0; q < 7; ++q) {
                const int li = i + q - 6;     // out w = wbase + li
                if (li >= 0 && li < 16) acc[li] += dynr[q] * cm;
            }
        }
    }
    const size_t obase = ((size_t)(b * 64 + h) * 64 + wbase) * MID_ + c;
#pragma unroll
    for (int li = 0; li < 16; ++li)
        outc[obase + (size_t)li * MID_] = (__bf16)acc[li];
}

// ---------------------------------------------------------------------------
// K7: up GEMM + bias + residual: out = a_in[32768,96] @ up_w[768,96]^T
//                                      + up_b + x   (fp32 out)
// Block: 256 thr, M-tile 32 (2 row-groups), N=768 split 2 ways (384/wave).
// ---------------------------------------------------------------------------
__global__ __launch_bounds__(256) void k_up(const __bf16* __restrict__ a_in,
        const float* __restrict__ upw, const float* __restrict__ upb,
        const float* __restrict__ x, float* __restrict__ out) {
    __shared__ bf16x8 As[32][4];
    __shared__ bf16x8 Bs[768][4];
    const int t = threadIdx.x;
    const int row0 = blockIdx.x * 32;
    const int lane = t & 63, wave = t >> 6;
    const int l15 = lane & 15, l4 = lane >> 4;
    const int mrow = (wave & 1) * 16;
    const int ncol0 = (wave >> 1) * 384;
    f32x4 acc[24] = {};
    for (int kt = 0; kt < 3; ++kt) {
        const int k0 = kt * 32;
        if (kt) __syncthreads();
        if (t < 128) {
            const int r = t >> 2, q = t & 3;
            As[r][q ^ (r & 3)] = *reinterpret_cast<const bf16x8*>(
                a_in + (size_t)(row0 + r) * MID_ + k0 + q * 8);
        }
        for (int idx = t; idx < 3072; idx += 256) {
            const int r = idx >> 2, q = idx & 3;
            const float* wp = upw + (size_t)r * MID_ + k0 + q * 8;
            float4 v0 = *reinterpret_cast<const float4*>(wp);
            float4 v1 = *reinterpret_cast<const float4*>(wp + 4);
            bf16x8 pk;
            pk[0] = (__bf16)v0.x; pk[1] = (__bf16)v0.y;
            pk[2] = (__bf16)v0.z; pk[3] = (__bf16)v0.w;
            pk[4] = (__bf16)v1.x; pk[5] = (__bf16)v1.y;
            pk[6] = (__bf16)v1.z; pk[7] = (__bf16)v1.w;
            Bs[r][q ^ (r & 3)] = pk;
        }
        __syncthreads();
        const int ar = mrow + l15;
        bf16x8 a = As[ar][l4 ^ (ar & 3)];
#pragma unroll
        for (int f = 0; f < 24; ++f) {
            const int br = ncol0 + f * 16 + l15;
            bf16x8 b = Bs[br][l4 ^ (br & 3)];
            acc[f] = __builtin_amdgcn_mfma_f32_16x16x32_bf16(a, b, acc[f], 0, 0, 0);
        }
    }
    const int orow = row0 + mrow + l4 * 4;
#pragma unroll
    for (int f = 0; f < 24; ++f) {
        const int col = ncol0 + f * 16 + l15;
        const float ub = upb[col];
#pragma unroll
        for (int r = 0; r < 4; ++r) {
            const size_t idx = (size_t)(orow + r) * DIM_ + col;
            out[idx] = acc[f][r] + ub + x[idx];
        }
    }
}

// ---------------------------------------------------------------------------
extern "C" void kernel_launch(void* const* d_in, const int* in_sizes, int n_in,
                              void* d_out, int out_size, void* d_ws, size_t ws_size,
                              hipStream_t stream) {
    (void)in_sizes; (void)n_in; (void)out_size; (void)ws_size;
    const float* x      = (const float*)d_in[0];
    const float* tt     = (const float*)d_in[1];
    const float* ln_w   = (const float*)d_in[2];
    const float* ln_b   = (const float*)d_in[3];
    const float* down_w = (const float*)d_in[4];
    const float* down_b = (const float*)d_in[5];
    const float* ln1_w  = (const float*)d_in[6];
    const float* ln1_b  = (const float*)d_in[7];
    const float* down1_w= (const float*)d_in[8];
    const float* down1_b= (const float*)d_in[9];
    const float* dw_w   = (const float*)d_in[10];
    const float* dw_b   = (const float*)d_in[11];
    const float* pw_w   = (const float*)d_in[12];
    const float* pw_b   = (const float*)d_in[13];
    const float* m1w    = (const float*)d_in[14];
    const float* m1b    = (const float*)d_in[15];
    const float* m2w    = (const float*)d_in[16];
    const float* m2b    = (const float*)d_in[17];
    const float* basis  = (const float*)d_in[18];
    const float* up_w   = (const float*)d_in[19];
    const float* up_b   = (const float*)d_in[20];
    float* out = (float*)d_out;
    char* ws = (char*)d_ws;

    // workspace layout (bytes) -- ~44.6 MB total
    float*  stats_x = (float*)(ws + 0);             // 32768*2*4    = 256 KB
    float*  stats_t = (float*)(ws + 262144);        // 256 KB
    float*  x_emb   = (float*)(ws + 524288);        // 32768*96*4   = 12.6 MB
    float*  t_emb   = (float*)(ws + 13107200);      // 12.6 MB
    __bf16* ybuf    = (__bf16*)(ws + 25690112);     // 32768*96*2   = 6.3 MB
    __bf16* common  = (__bf16*)(ws + 31981568);     // 6.3 MB
    __bf16* convout = (__bf16*)(ws + 38273024);     // 6.3 MB
    float*  part    = (float*)(ws + 44564480);      // 8*16*96*4    = 48 KB
    float*  wts     = (float*)(ws + 44613632);      // 8*4*4

    k_stats<<<8192, 256, 0, stream>>>(x, stats_x);
    k_stats<<<8192, 256, 0, stream>>>(tt, stats_t);
    k_down<<<512, 256, 0, stream>>>(x, stats_x, down_w, down_b, ln_w, ln_b, x_emb);
    k_down<<<512, 256, 0, stream>>>(tt, stats_t, down1_w, down1_b, ln1_w, ln1_b, t_emb);
    k_gvec<<<dim3(8, 16), 384, 0, stream>>>(x_emb, part);
    k_mlp<<<8, 128, 0, stream>>>(part, m1w, m1b, m2w, m2b, wts);
    k_dwconv<<<512, 256, 0, stream>>>(t_emb, dw_w, dw_b, ybuf);
    k_style<<<512, 256, 0, stream>>>(ybuf, pw_w, pw_b, x_emb, common);
    k_circ<<<1024, 192, 0, stream>>>(common, wts, basis, convout);
    k_up<<<1024, 256, 0, stream>>>(convout, up_w, up_b, x, out);
}

// Round 2
// 246.149 us; speedup vs baseline: 1.2523x; 1.2523x over previous
//
#include <hip/hip_runtime.h>

#define DIM_ 768
#define MID_ 96

typedef float f32x4 __attribute__((ext_vector_type(4)));
typedef __bf16 bf16x8 __attribute__((ext_vector_type(8)));
typedef __bf16 bf16x4 __attribute__((ext_vector_type(4)));

// ---------------------------------------------------------------------------
// K_wprep: fp32->bf16 weight pre-conversion (down_w, down1_w, up_w, pw_w)
// + zero the gvec partial buffer. One thread = one float4.
// ---------------------------------------------------------------------------
__global__ __launch_bounds__(256) void k_wprep(const float* __restrict__ dw,
        const float* __restrict__ d1w, const float* __restrict__ uw,
        const float* __restrict__ pw, __bf16* __restrict__ bdw,
        __bf16* __restrict__ bd1, __bf16* __restrict__ bup,
        __bf16* __restrict__ bpw, float* __restrict__ part) {
    const int t = blockIdx.x * 256 + threadIdx.x;
    const float* src;
    __bf16* dst;
    int i;
    if (t < 18432)      { src = dw;  dst = bdw; i = t; }
    else if (t < 36864) { src = d1w; dst = bd1; i = t - 18432; }
    else if (t < 55296) { src = uw;  dst = bup; i = t - 36864; }
    else if (t < 59904) { src = pw;  dst = bpw; i = t - 55296; }
    else if (t < 60672) { part[t - 59904] = 0.f; return; }
    else return;
    float4 v = reinterpret_cast<const float4*>(src)[i];
    bf16x4 o;
    o[0] = (__bf16)v.x; o[1] = (__bf16)v.y; o[2] = (__bf16)v.z; o[3] = (__bf16)v.w;
    *reinterpret_cast<bf16x4*>(dst + (size_t)i * 4) = o;
}

// ---------------------------------------------------------------------------
// K_down: fused LayerNorm (inline stats) + GEMM  out = LN(src) @ wbf^T + bias
// src [32768,768] fp32, wbf [96,768] bf16, outb [32768,96] bf16.
// Phase 0: 4 threads/row compute mean/rstd (butterfly, kept in registers).
// Phase 1: 24 K-tiles of 32; A normalized+cast on the fly; B is bf16 copy.
// If part != nullptr: per-wave column sums atomicAdd'ed (gvec fusion).
// ---------------------------------------------------------------------------
__global__ __launch_bounds__(256) void k_down(const float* __restrict__ src,
        const __bf16* __restrict__ wbf, const float* __restrict__ bias,
        const float* __restrict__ lnw, const float* __restrict__ lnb,
        __bf16* __restrict__ outb, float* __restrict__ part) {
    __shared__ bf16x8 As[64][5];   // 4 data slots + 1 pad (80B row stride)
    __shared__ bf16x8 Bs[96][5];
    const int t = threadIdx.x;
    const int row0 = blockIdx.x * 64;
    const int r = t >> 2, s4 = t & 3;
    const float* rp = src + (size_t)(row0 + r) * DIM_;

    // phase 0: stats for own row (4-thread group per row)
    float s = 0.f, sq = 0.f;
#pragma unroll 4
    for (int j = 0; j < 48; ++j) {
        float4 v = *reinterpret_cast<const float4*>(rp + j * 16 + s4 * 4);
        s += v.x + v.y + v.z + v.w;
        sq += v.x * v.x + v.y * v.y + v.z * v.z + v.w * v.w;
    }
    s += __shfl_xor(s, 1, 64); sq += __shfl_xor(sq, 1, 64);
    s += __shfl_xor(s, 2, 64); sq += __shfl_xor(sq, 2, 64);
    const float mean = s * (1.f / 768.f);
    const float rstd = rsqrtf(sq * (1.f / 768.f) - mean * mean + 1e-6f);

    const int lane = t & 63, wave = t >> 6;
    const int l15 = lane & 15, l4 = lane >> 4;
    f32x4 acc[6] = {};

    for (int kt = 0; kt < 24; ++kt) {
        const int k0 = kt * 32;
        if (kt) __syncthreads();
        // A stage: normalize + cast (re-read hits L2/L3)
        {
            float4 v0 = *reinterpret_cast<const float4*>(rp + k0 + s4 * 8);
            float4 v1 = *reinterpret_cast<const float4*>(rp + k0 + s4 * 8 + 4);
            const float* lwp = lnw + k0 + s4 * 8;
            const float* lbp = lnb + k0 + s4 * 8;
            float4 w0 = *reinterpret_cast<const float4*>(lwp);
            float4 w1 = *reinterpret_cast<const float4*>(lwp + 4);
            float4 b0 = *reinterpret_cast<const float4*>(lbp);
            float4 b1 = *reinterpret_cast<const float4*>(lbp + 4);
            bf16x8 pk;
            pk[0] = (__bf16)((v0.x - mean) * rstd * w0.x + b0.x);
            pk[1] = (__bf16)((v0.y - mean) * rstd * w0.y + b0.y);
            pk[2] = (__bf16)((v0.z - mean) * rstd * w0.z + b0.z);
            pk[3] = (__bf16)((v0.w - mean) * rstd * w0.w + b0.w);
            pk[4] = (__bf16)((v1.x - mean) * rstd * w1.x + b1.x);
            pk[5] = (__bf16)((v1.y - mean) * rstd * w1.y + b1.y);
            pk[6] = (__bf16)((v1.z - mean) * rstd * w1.z + b1.z);
            pk[7] = (__bf16)((v1.w - mean) * rstd * w1.w + b1.w);
            As[r][s4] = pk;
        }
        // B stage: 96 rows x 4 slots, direct bf16 16B copies
#pragma unroll
        for (int it = 0; it < 2; ++it) {
            const int idx = t + it * 256;
            if (idx < 384) {
                const int br = idx >> 2, bq = idx & 3;
                Bs[br][bq] = *reinterpret_cast<const bf16x8*>(
                    wbf + (size_t)br * DIM_ + k0 + bq * 8);
            }
        }
        __syncthreads();
        bf16x8 a = As[wave * 16 + l15][l4];
#pragma unroll
        for (int f = 0; f < 6; ++f) {
            bf16x8 b = Bs[f * 16 + l15][l4];
            acc[f] = __builtin_amdgcn_mfma_f32_16x16x32_bf16(a, b, acc[f], 0, 0, 0);
        }
    }
    // epilogue: bf16 store + optional fused gvec partial (atomic per col)
    const int orow = row0 + wave * 16 + l4 * 4;
    const int batch = blockIdx.x >> 6;
#pragma unroll
    for (int f = 0; f < 6; ++f) {
        const int col = f * 16 + l15;
        const float bc = bias[col];
        float cs = 0.f;
#pragma unroll
        for (int rr = 0; rr < 4; ++rr) {
            const float val = acc[f][rr] + bc;
            outb[(size_t)(orow + rr) * MID_ + col] = (__bf16)val;
            cs += val;
        }
        if (part) {
            cs += __shfl_xor(cs, 16, 64);
            cs += __shfl_xor(cs, 32, 64);
            if (l4 == 0) atomicAdd(&part[batch * MID_ + col], cs);
        }
    }
}

// ---------------------------------------------------------------------------
// K_mlp: gvec mean from part, MLP (96->24 relu ->4), softmax -> wts [8,4]
// ---------------------------------------------------------------------------
__global__ __launch_bounds__(128) void k_mlp(const float* __restrict__ part,
        const float* __restrict__ m1w, const float* __restrict__ m1b,
        const float* __restrict__ m2w, const float* __restrict__ m2b,
        float* __restrict__ wts) {
    const int b = blockIdx.x, t = threadIdx.x;
    __shared__ float gv[96];
    __shared__ float hid[24];
    __shared__ float lg[4];
    if (t < 96) gv[t] = part[b * MID_ + t] * (1.f / 4096.f);
    __syncthreads();
    if (t < 24) {
        float s = m1b[t];
        for (int c = 0; c < 96; ++c) s += gv[c] * m1w[t * 96 + c];
        hid[t] = fmaxf(s, 0.f);
    }
    __syncthreads();
    if (t < 4) {
        float s = m2b[t];
        for (int j = 0; j < 24; ++j) s += hid[j] * m2w[t * 24 + j];
        lg[t] = s;
    }
    __syncthreads();
    if (t < 4) {
        const float m = fmaxf(fmaxf(lg[0], lg[1]), fmaxf(lg[2], lg[3]));
        const float e = __expf(lg[t] - m);
        const float sum = __expf(lg[0] - m) + __expf(lg[1] - m) +
                          __expf(lg[2] - m) + __expf(lg[3] - m);
        wts[b * 4 + t] = e / sum;
    }
}

// ---------------------------------------------------------------------------
// K_dwconv: depthwise 3x3 conv (zero pad) + SiLU. temb bf16 -> y bf16.
// ---------------------------------------------------------------------------
__global__ __launch_bounds__(256) void k_dwconv(const __bf16* __restrict__ temb,
        const float* __restrict__ dww, const float* __restrict__ dwb,
        __bf16* __restrict__ y) {
    __shared__ float wls[96 * 9];
    __shared__ float bls[96];
    const int t = threadIdx.x;
    for (int i = t; i < 96 * 9; i += 256) wls[i] = dww[i];
    if (t < 96) bls[t] = dwb[t];
    __syncthreads();
    const int b = blockIdx.x >> 6, h = blockIdx.x & 63;
    const __bf16* base = temb + (size_t)b * 4096 * MID_;
    for (int o = t; o < 64 * 96; o += 256) {
        const int w = o / 96;
        const int c = o - w * 96;
        float acc = bls[c];
#pragma unroll
        for (int dh = 0; dh < 3; ++dh) {
            const int hh = h + dh - 1;
            if (hh < 0 || hh > 63) continue;
#pragma unroll
            for (int dw = 0; dw < 3; ++dw) {
                const int ww = w + dw - 1;
                if (ww < 0 || ww > 63) continue;
                acc += (float)base[((size_t)hh * 64 + ww) * MID_ + c] *
                       wls[c * 9 + dh * 3 + dw];
            }
        }
        y[((size_t)(b * 64 + h) * 64 + w) * MID_ + c] =
            (__bf16)(acc / (1.f + __expf(-acc)));
    }
}

// ---------------------------------------------------------------------------
// K_style: style GEMM (y @ pw_w^T + pw_b) fused with modulation:
// common = x_emb * (1 + gamma) + beta -> bf16. K=96 fully staged, 1 barrier.
// ---------------------------------------------------------------------------
__global__ __launch_bounds__(256) void k_style(const __bf16* __restrict__ y,
        const __bf16* __restrict__ wpw, const float* __restrict__ pwb,
        const __bf16* __restrict__ xemb, __bf16* __restrict__ common) {
    __shared__ bf16x8 As[64][13];    // 12 data slots + pad
    __shared__ bf16x8 Bs[192][13];
    const int t = threadIdx.x;
    const int row0 = blockIdx.x * 64;
    for (int idx = t; idx < 768; idx += 256) {
        const int rr = idx / 12, q = idx - rr * 12;
        As[rr][q] = *reinterpret_cast<const bf16x8*>(
            y + (size_t)(row0 + rr) * MID_ + q * 8);
    }
    for (int idx = t; idx < 2304; idx += 256) {
        const int rr = idx / 12, q = idx - rr * 12;
        Bs[rr][q] = *reinterpret_cast<const bf16x8*>(
            wpw + (size_t)rr * MID_ + q * 8);
    }
    __syncthreads();
    const int lane = t & 63, wave = t >> 6;
    const int l15 = lane & 15, l4 = lane >> 4;
    f32x4 acc[12] = {};
    const int ar = wave * 16 + l15;
#pragma unroll
    for (int kt = 0; kt < 3; ++kt) {
        bf16x8 a = As[ar][kt * 4 + l4];
#pragma unroll
        for (int f = 0; f < 12; ++f) {
            bf16x8 b = Bs[f * 16 + l15][kt * 4 + l4];
            acc[f] = __builtin_amdgcn_mfma_f32_16x16x32_bf16(a, b, acc[f], 0, 0, 0);
        }
    }
    const int orow = row0 + wave * 16 + l4 * 4;
#pragma unroll
    for (int f = 0; f < 6; ++f) {
        const int col = f * 16 + l15;
        const float pbg = pwb[col];
        const float pbb = pwb[col + 96];
#pragma unroll
        for (int rr = 0; rr < 4; ++rr) {
            const float g = acc[f][rr] + pbg;
            const float bt = acc[f + 6][rr] + pbb;
            const float xe = (float)xemb[(size_t)(orow + rr) * MID_ + col];
            common[(size_t)(orow + rr) * MID_ + col] = (__bf16)(xe * (1.f + g) + bt);
        }
    }
}

// ---------------------------------------------------------------------------
// K_circ: circular 7x7 conv (== rfft2/irfft2 product). dyn built in LDS.
// ---------------------------------------------------------------------------
__global__ __launch_bounds__(192) void k_circ(const __bf16* __restrict__ common,
        const float* __restrict__ wts, const float* __restrict__ basis,
        __bf16* __restrict__ outc) {
    __shared__ float dyn[49][96];
    const int t = threadIdx.x;
    const int b = blockIdx.x >> 7;
    const int h = (blockIdx.x >> 1) & 63;
    const int wslice = blockIdx.x & 1;
    const float w0 = wts[b * 4 + 0], w1 = wts[b * 4 + 1];
    const float w2 = wts[b * 4 + 2], w3 = wts[b * 4 + 3];
    for (int idx = t; idx < 4704; idx += 192) {
        const int c = idx / 49;
        const int pq = idx - c * 49;
        const size_t off = (size_t)c * 49 + pq;
        dyn[pq][c] = w0 * basis[off] + w1 * basis[off + 4704] +
                     w2 * basis[off + 9408] + w3 * basis[off + 14112];
    }
    __syncthreads();
    const int c = t % 96;
    const int wg = t / 96;
    const int wbase = wslice * 32 + wg * 16;
    const __bf16* cb = common + (size_t)b * 4096 * MID_ + c;
    float acc[16] = {};
#pragma unroll 1
    for (int p = 0; p < 7; ++p) {
        const int hh = (h + 3 - p) & 63;
        const __bf16* rp = cb + (size_t)hh * 64 * MID_;
        float dynr[7];
#pragma unroll
        for (int q = 0; q < 7; ++q) dynr[q] = dyn[p * 7 + q][c];
#pragma unroll
        for (int i = 0; i < 22; ++i) {
            const int ww = (wbase - 3 + i) & 63;
            const float cm = (float)rp[(size_t)ww * MID_];
#pragma unroll
            for (int q = 0; q < 7; ++q) {
                const int li = i + q - 6;
                if (li >= 0 && li < 16) acc[li] += dynr[q] * cm;
            }
        }
    }
    const size_t obase = ((size_t)(b * 64 + h) * 64 + wbase) * MID_ + c;
#pragma unroll
    for (int li = 0; li < 16; ++li)
        outc[obase + (size_t)li * MID_] = (__bf16)acc[li];
}

// ---------------------------------------------------------------------------
// K_up: out = a_in[32768,96] @ up_w_bf16[768,96]^T + up_b + x  (fp32 out)
// M-tile 128 x N-tile 96, K=96 fully LDS-staged, one barrier, 36 MFMA/wave.
// Consecutive blocks share the A-tile (ntile in low bits) for L2 locality.
// ---------------------------------------------------------------------------
__global__ __launch_bounds__(256) void k_up(const __bf16* __restrict__ a_in,
        const __bf16* __restrict__ wbf, const float* __restrict__ upb,
        const float* __restrict__ x, float* __restrict__ out) {
    __shared__ bf16x8 As[128][13];
    __shared__ bf16x8 Ws[96][13];
    const int t = threadIdx.x;
    const int mt = blockIdx.x >> 3, nt = blockIdx.x & 7;
    const int row0 = mt * 128, col0 = nt * 96;
    for (int idx = t; idx < 1536; idx += 256) {
        const int rr = idx / 12, q = idx - rr * 12;
        As[rr][q] = *reinterpret_cast<const bf16x8*>(
            a_in + (size_t)(row0 + rr) * MID_ + q * 8);
    }
    for (int idx = t; idx < 1152; idx += 256) {
        const int rr = idx / 12, q = idx - rr * 12;
        Ws[rr][q] = *reinterpret_cast<const bf16x8*>(
            wbf + (size_t)(col0 + rr) * MID_ + q * 8);
    }
    __syncthreads();
    const int lane = t & 63, wave = t >> 6;
    const int l15 = lane & 15, l4 = lane >> 4;
    f32x4 acc[2][6] = {};
#pragma unroll
    for (int kt = 0; kt < 3; ++kt) {
        bf16x8 a0 = As[wave * 32 + l15][kt * 4 + l4];
        bf16x8 a1 = As[wave * 32 + 16 + l15][kt * 4 + l4];
#pragma unroll
        for (int f = 0; f < 6; ++f) {
            bf16x8 b = Ws[f * 16 + l15][kt * 4 + l4];
            acc[0][f] = __builtin_amdgcn_mfma_f32_16x16x32_bf16(a0, b, acc[0][f], 0, 0, 0);
            acc[1][f] = __builtin_amdgcn_mfma_f32_16x16x32_bf16(a1, b, acc[1][f], 0, 0, 0);
        }
    }
#pragma unroll
    for (int mr = 0; mr < 2; ++mr) {
        const int orow = row0 + wave * 32 + mr * 16 + l4 * 4;
#pragma unroll
        for (int f = 0; f < 6; ++f) {
            const int col = col0 + f * 16 + l15;
            const float ub = upb[col];
#pragma unroll
            for (int rr = 0; rr < 4; ++rr) {
                const size_t idx = (size_t)(orow + rr) * DIM_ + col;
                out[idx] = acc[mr][f][rr] + ub + x[idx];
            }
        }
    }
}

// ---------------------------------------------------------------------------
extern "C" void kernel_launch(void* const* d_in, const int* in_sizes, int n_in,
                              void* d_out, int out_size, void* d_ws, size_t ws_size,
                              hipStream_t stream) {
    (void)in_sizes; (void)n_in; (void)out_size; (void)ws_size;
    const float* x      = (const float*)d_in[0];
    const float* tt     = (const float*)d_in[1];
    const float* ln_w   = (const float*)d_in[2];
    const float* ln_b   = (const float*)d_in[3];
    const float* down_w = (const float*)d_in[4];
    const float* down_b = (const float*)d_in[5];
    const float* ln1_w  = (const float*)d_in[6];
    const float* ln1_b  = (const float*)d_in[7];
    const float* down1_w= (const float*)d_in[8];
    const float* down1_b= (const float*)d_in[9];
    const float* dw_w   = (const float*)d_in[10];
    const float* dw_b   = (const float*)d_in[11];
    const float* pw_w   = (const float*)d_in[12];
    const float* pw_b   = (const float*)d_in[13];
    const float* m1w    = (const float*)d_in[14];
    const float* m1b    = (const float*)d_in[15];
    const float* m2w    = (const float*)d_in[16];
    const float* m2b    = (const float*)d_in[17];
    const float* basis  = (const float*)d_in[18];
    const float* up_w   = (const float*)d_in[19];
    const float* up_b   = (const float*)d_in[20];
    float* out = (float*)d_out;
    char* ws = (char*)d_ws;

    // workspace layout (bytes)
    __bf16* wbf_down  = (__bf16*)(ws + 0);          // 96*768*2  = 147456
    __bf16* wbf_down1 = (__bf16*)(ws + 147456);
    __bf16* wbf_up    = (__bf16*)(ws + 294912);     // 768*96*2
    __bf16* wbf_pw    = (__bf16*)(ws + 442368);     // 192*96*2 = 36864
    float*  part      = (float*)(ws + 479232);      // 8*96*4 = 3072
    float*  wts       = (float*)(ws + 482304);      // 32*4
    __bf16* x_emb     = (__bf16*)(ws + 524288);     // 32768*96*2 = 6291456
    __bf16* t_emb     = (__bf16*)(ws + 6815744);
    __bf16* ybuf      = (__bf16*)(ws + 13107200);
    __bf16* common    = (__bf16*)(ws + 19398656);
    __bf16* convout   = (__bf16*)(ws + 25690112);

    k_wprep<<<237, 256, 0, stream>>>(down_w, down1_w, up_w, pw_w,
                                     wbf_down, wbf_down1, wbf_up, wbf_pw, part);
    k_down<<<512, 256, 0, stream>>>(x, wbf_down, down_b, ln_w, ln_b, x_emb, part);
    k_down<<<512, 256, 0, stream>>>(tt, wbf_down1, down1_b, ln1_w, ln1_b, t_emb, nullptr);
    k_mlp<<<8, 128, 0, stream>>>(part, m1w, m1b, m2w, m2b, wts);
    k_dwconv<<<512, 256, 0, stream>>>(t_emb, dw_w, dw_b, ybuf);
    k_style<<<512, 256, 0, stream>>>(ybuf, wbf_pw, pw_b, x_emb, common);
    k_circ<<<1024, 192, 0, stream>>>(common, wts, basis, convout);
    k_up<<<2048, 256, 0, stream>>>(convout, wbf_up, up_b, x, out);
}